// Round 5
// baseline (47.733 us; speedup 1.0000x reference)
//
#include <hip/hip_runtime.h>
#include <hip/hip_bf16.h>
#include <math.h>

#define DEPTH    11
#define NNODES   4095
#define DIN      768
#define NTOK     8192

// ---------------------------------------------------------------------------
// Transpose + bf16-quantize w_out [768][4095] f32  ->  wT [4095][768] bf16.
// ---------------------------------------------------------------------------
__global__ __launch_bounds__(256) void fff_transpose_bf16(const float* __restrict__ src,
                                                          __hip_bfloat16* __restrict__ dst) {
    __shared__ float tile[32][33];
    const int n0 = blockIdx.x * 32;  // node dim (4095)
    const int j0 = blockIdx.y * 32;  // feature dim (768)
    const int tx = threadIdx.x, ty = threadIdx.y;
#pragma unroll
    for (int i = 0; i < 32; i += 8) {
        const int j = j0 + ty + i;
        const int n = n0 + tx;
        if (n < NNODES) tile[ty + i][tx] = src[(size_t)j * NNODES + n];
    }
    __syncthreads();
#pragma unroll
    for (int i = 0; i < 32; i += 8) {
        const int n = n0 + ty + i;
        const int j = j0 + tx;
        if (n < NNODES) dst[(size_t)n * DIN + j] = __float2bfloat16(tile[tx][ty + i]);
    }
}

__device__ __forceinline__ float bf_lo(unsigned u) {
    union { unsigned v; float f; } c; c.v = u << 16; return c.f;
}
__device__ __forceinline__ float bf_hi(unsigned u) {
    union { unsigned v; float f; } c; c.v = u & 0xffff0000u; return c.f;
}

// ---------------------------------------------------------------------------
// Walk kernel, SIMD-over-tokens: one 64-lane wave carries FOUR tokens as
// 4 x 16-lane groups. All four tree walks advance in the same instructions,
// so per-level latency (row load + f64 dot + reduce) is paid once per wave,
// not once per token, and the butterfly reduce is 4 steps (within 16 lanes)
// instead of 6. Group g's row load covers 256B contiguous per instruction.
// Products in f64 (exact), so decisions match prior passing rounds.
// ---------------------------------------------------------------------------
__global__ __launch_bounds__(256) void fff_walk4(const float* __restrict__ x,
                                                 const float* __restrict__ w_in,
                                                 int* __restrict__ nd_out,
                                                 float* __restrict__ g_out) {
    const int wid   = (int)((blockIdx.x * blockDim.x + threadIdx.x) >> 6);
    const int lane  = (int)(threadIdx.x & 63);
    const int chain = lane >> 4;   // 0..3  (token within wave)
    const int slot  = lane & 15;   // 0..15 (position within chain)
    const int token = wid * 4 + chain;

    // Slot covers float4 indices slot + 16*k, k = 0..11  (192 float4 = 768 f32).
    const float4* xr = reinterpret_cast<const float4*>(x + (size_t)token * DIN);
    float4 xv[12];
#pragma unroll
    for (int k = 0; k < 12; ++k) xv[k] = xr[slot + 16 * k];

    int cur = 0;
#pragma unroll
    for (int d = 0; d <= DEPTH; ++d) {
        const float4* wr = reinterpret_cast<const float4*>(w_in + (size_t)cur * DIN);

        // 4 rotating f64 accumulators; loads stream, compiler pipelines vmcnt.
        double p0 = 0.0, p1 = 0.0, p2 = 0.0, p3 = 0.0;
#pragma unroll
        for (int k = 0; k < 12; k += 4) {
            const float4 w0 = wr[slot + 16 * (k + 0)];
            const float4 w1 = wr[slot + 16 * (k + 1)];
            const float4 w2 = wr[slot + 16 * (k + 2)];
            const float4 w3 = wr[slot + 16 * (k + 3)];
            p0 += (double)xv[k + 0].x * w0.x; p0 += (double)xv[k + 0].y * w0.y;
            p0 += (double)xv[k + 0].z * w0.z; p0 += (double)xv[k + 0].w * w0.w;
            p1 += (double)xv[k + 1].x * w1.x; p1 += (double)xv[k + 1].y * w1.y;
            p1 += (double)xv[k + 1].z * w1.z; p1 += (double)xv[k + 1].w * w1.w;
            p2 += (double)xv[k + 2].x * w2.x; p2 += (double)xv[k + 2].y * w2.y;
            p2 += (double)xv[k + 2].z * w2.z; p2 += (double)xv[k + 2].w * w2.w;
            p3 += (double)xv[k + 3].x * w3.x; p3 += (double)xv[k + 3].y * w3.y;
            p3 += (double)xv[k + 3].z * w3.z; p3 += (double)xv[k + 3].w * w3.w;
        }
        double part = (p0 + p1) + (p2 + p3);

        // 4-step butterfly within the 16-lane group (xor masks < 16).
#pragma unroll
        for (int off = 8; off >= 1; off >>= 1) part += __shfl_xor(part, off);

        if (slot == 0) {
            const float lg = (float)part;
            g_out[token * 12 + d]  = 0.5f * lg * (1.0f + erff(lg * 0.7071067811865476f));
            nd_out[token * 12 + d] = cur;
        }
        if (d < DEPTH) cur = 2 * cur + 1 + (part > 0.0 ? 1 : 0);
    }
}

// ---------------------------------------------------------------------------
// Gather kernel: one wave per token; 36 fully independent bf16 row loads.
// ---------------------------------------------------------------------------
__global__ __launch_bounds__(256) void fff_gather(const __hip_bfloat16* __restrict__ wT,
                                                  const int* __restrict__ nd_in,
                                                  const float* __restrict__ g_in,
                                                  float* __restrict__ out) {
    const int token = (int)((blockIdx.x * blockDim.x + threadIdx.x) >> 6);
    const int lane  = (int)(threadIdx.x & 63);

    float gv = 0.f; int nv = 0;
    if (lane < 12) {
        gv = g_in[token * 12 + lane];
        nv = nd_in[token * 12 + lane];
    }

    float acc[12];
#pragma unroll
    for (int i = 0; i < 12; ++i) acc[i] = 0.f;

#pragma unroll
    for (int d = 0; d <= DEPTH; ++d) {
        const float gg = __shfl(gv, d);
        const int   nn = __shfl(nv, d);
        const uint2* row = reinterpret_cast<const uint2*>(wT + (size_t)nn * DIN);
#pragma unroll
        for (int k = 0; k < 3; ++k) {
            const uint2 v = row[lane + 64 * k];
            acc[k * 4 + 0] = fmaf(gg, bf_lo(v.x), acc[k * 4 + 0]);
            acc[k * 4 + 1] = fmaf(gg, bf_hi(v.x), acc[k * 4 + 1]);
            acc[k * 4 + 2] = fmaf(gg, bf_lo(v.y), acc[k * 4 + 2]);
            acc[k * 4 + 3] = fmaf(gg, bf_hi(v.y), acc[k * 4 + 3]);
        }
    }

    float4* orow = reinterpret_cast<float4*>(out + (size_t)token * DIN);
#pragma unroll
    for (int k = 0; k < 3; ++k)
        orow[k * 64 + lane] = make_float4(acc[k * 4 + 0], acc[k * 4 + 1],
                                          acc[k * 4 + 2], acc[k * 4 + 3]);
}

// ---------------------------------------------------------------------------
// Fallback (ws too small): round-1 fused kernel with strided f32 w_out reads.
// ---------------------------------------------------------------------------
__global__ __launch_bounds__(256) void fff_fused_fallback(const float* __restrict__ x,
                                                          const float* __restrict__ w_in,
                                                          const float* __restrict__ w_o,
                                                          float* __restrict__ out) {
    const int token = (int)((blockIdx.x * blockDim.x + threadIdx.x) >> 6);
    const int lane  = (int)(threadIdx.x & 63);

    const float4* xr = reinterpret_cast<const float4*>(x + (size_t)token * DIN);
    float4 xv[3];
#pragma unroll
    for (int k = 0; k < 3; ++k) xv[k] = xr[lane + 64 * k];
    float4 acc[3];
#pragma unroll
    for (int k = 0; k < 3; ++k) acc[k] = make_float4(0.f, 0.f, 0.f, 0.f);

    int cur = 0;
#pragma unroll
    for (int d = 0; d <= DEPTH; ++d) {
        const float4* wr = reinterpret_cast<const float4*>(w_in + (size_t)cur * DIN);
        double part = 0.0;
#pragma unroll
        for (int k = 0; k < 3; ++k) {
            const float4 w = wr[lane + 64 * k];
            part += (double)xv[k].x * w.x; part += (double)xv[k].y * w.y;
            part += (double)xv[k].z * w.z; part += (double)xv[k].w * w.w;
        }
#pragma unroll
        for (int off = 32; off >= 1; off >>= 1) part += __shfl_xor(part, off);
        const float logit = (float)part;
        const float gg = 0.5f * logit * (1.0f + erff(logit * 0.7071067811865476f));
#pragma unroll
        for (int k = 0; k < 3; ++k) {
            const int j = (lane + 64 * k) * 4;
            acc[k].x = fmaf(gg, w_o[(size_t)(j + 0) * NNODES + cur], acc[k].x);
            acc[k].y = fmaf(gg, w_o[(size_t)(j + 1) * NNODES + cur], acc[k].y);
            acc[k].z = fmaf(gg, w_o[(size_t)(j + 2) * NNODES + cur], acc[k].z);
            acc[k].w = fmaf(gg, w_o[(size_t)(j + 3) * NNODES + cur], acc[k].w);
        }
        if (d < DEPTH) cur = 2 * cur + 1 + (part > 0.0 ? 1 : 0);
    }
    float4* orow = reinterpret_cast<float4*>(out + (size_t)token * DIN);
#pragma unroll
    for (int k = 0; k < 3; ++k) orow[lane + 64 * k] = acc[k];
}

extern "C" void kernel_launch(void* const* d_in, const int* in_sizes, int n_in,
                              void* d_out, int out_size, void* d_ws, size_t ws_size,
                              hipStream_t stream) {
    const float* x     = (const float*)d_in[0];   // [8192, 768]
    const float* w_in  = (const float*)d_in[1];   // [4095, 768]
    const float* w_out = (const float*)d_in[2];   // [768, 4095]
    float*       out   = (float*)d_out;           // [8192, 768]

    const size_t wT_bytes = (size_t)NNODES * DIN * sizeof(__hip_bfloat16);  // 6,289,920
    const size_t nd_bytes = (size_t)NTOK * 12 * sizeof(int);                // 393,216
    const size_t g_bytes  = (size_t)NTOK * 12 * sizeof(float);              // 393,216
    const size_t need = wT_bytes + nd_bytes + g_bytes;                      // ~7.08 MB

    if (ws_size >= need) {
        char* ws = (char*)d_ws;
        __hip_bfloat16* wT = (__hip_bfloat16*)ws;
        int*   nd = (int*)(ws + wT_bytes);
        float* g  = (float*)(ws + wT_bytes + nd_bytes);

        dim3 tb(32, 8);
        dim3 tg((NNODES + 31) / 32, DIN / 32);
        hipLaunchKernelGGL(fff_transpose_bf16, tg, tb, 0, stream, w_out, wT);
        // 8192 tokens / 4 per wave = 2048 waves; 256 threads = 4 waves/block
        hipLaunchKernelGGL(fff_walk4, dim3(512), dim3(256), 0, stream, x, w_in, nd, g);
        hipLaunchKernelGGL(fff_gather, dim3(NTOK / 4), dim3(256), 0, stream, wT, nd, g, out);
    } else {
        hipLaunchKernelGGL(fff_fused_fallback, dim3(NTOK / 4), dim3(256), 0, stream,
                           x, w_in, w_out, out);
    }
}